// Round 1
// baseline (2507.339 us; speedup 1.0000x reference)
//
#include <hip/hip_runtime.h>
#include <math.h>

// Problem constants
constexpr int NN   = 50000;          // nodes
constexpr int NE   = 800000;         // edges (without self loops)
constexpr int EP   = NE + NN;        // edges + self loops = 850000
constexpr int FIN  = 500;
constexpr int C    = 128;
constexpr int NCLS = 7;
constexpr int NL   = 8;
constexpr float ALPHA = 0.1f;
constexpr float NEG_SLOPE = 0.2f;

// ---------------- utility fills ----------------
__global__ void fill_i32_k(int* p, int v, int n) {
    int i = blockIdx.x * blockDim.x + threadIdx.x;
    if (i < n) p[i] = v;
}
__global__ void fill_f32_k(float* p, float v, int n) {
    int i = blockIdx.x * blockDim.x + threadIdx.x;
    if (i < n) p[i] = v;
}

// ---------------- graph prep ----------------
__global__ void count_deg_k(const int* __restrict__ dst, int* __restrict__ deg, int e) {
    int i = blockIdx.x * blockDim.x + threadIdx.x;
    if (i < e) atomicAdd(&deg[dst[i]], 1);
}

__global__ void dinv_k(const int* __restrict__ deg, float* __restrict__ dinv, int n) {
    int i = blockIdx.x * blockDim.x + threadIdx.x;
    if (i < n) dinv[i] = rsqrtf((float)deg[i]);
}

// single-block hierarchical exclusive scan of deg -> offs (and cursor copy)
__global__ __launch_bounds__(1024) void scan_k(const int* __restrict__ deg,
                                               int* __restrict__ offs,
                                               int* __restrict__ cursor, int n) {
    __shared__ int sums[1024];
    int t = threadIdx.x;
    int chunk = (n + 1023) >> 10;
    int base = t * chunk;
    int s = 0;
    for (int j = 0; j < chunk; ++j) {
        int i = base + j;
        if (i < n) s += deg[i];
    }
    sums[t] = s;
    __syncthreads();
    for (int off = 1; off < 1024; off <<= 1) {
        int v = (t >= off) ? sums[t - off] : 0;
        __syncthreads();
        sums[t] += v;
        __syncthreads();
    }
    int run = (t == 0) ? 0 : sums[t - 1];
    for (int j = 0; j < chunk; ++j) {
        int i = base + j;
        if (i < n) { offs[i] = run; cursor[i] = run; run += deg[i]; }
    }
    if (t == 0) offs[n] = sums[1023];
}

__global__ void ew_k(const int* __restrict__ src, const int* __restrict__ dst,
                     const float* __restrict__ dinv, float* __restrict__ ew) {
    int e = blockIdx.x * blockDim.x + threadIdx.x;
    if (e >= EP) return;
    if (e < NE) ew[e] = dinv[src[e]] * dinv[dst[e]];
    else { float d = dinv[e - NE]; ew[e] = d * d; }
}

__global__ void csr_fill_k(const int* __restrict__ src, const int* __restrict__ dst,
                           int* __restrict__ cursor, int* __restrict__ csr_src,
                           int* __restrict__ csr_eid) {
    int e = blockIdx.x * blockDim.x + threadIdx.x;
    if (e >= EP) return;
    int s, d;
    if (e < NE) { s = src[e]; d = dst[e]; }
    else { s = d = e - NE; }
    int pos = atomicAdd(&cursor[d], 1);
    csr_src[pos] = s;
    csr_eid[pos] = e;
}

// alp[l] = lin_w[l] @ att_l[l]; arp[l] = lin_w[l] @ att_r[l]
__global__ void attproj_k(const float* __restrict__ lin_w, const float* __restrict__ att_l,
                          const float* __restrict__ att_r, float* __restrict__ alp,
                          float* __restrict__ arp) {
    __shared__ float al[C], ar[C];
    int l = blockIdx.x;          // layer
    int k = threadIdx.x;         // 0..127
    al[k] = att_l[l * C + k];
    ar[k] = att_r[l * C + k];
    __syncthreads();
    const float* w = lin_w + (size_t)l * C * C + (size_t)k * C;  // row k of lin_w[l]
    float s1 = 0.f, s2 = 0.f;
    #pragma unroll 8
    for (int c = 0; c < C; ++c) { float v = w[c]; s1 += v * al[c]; s2 += v * ar[c]; }
    alp[l * C + k] = s1;
    arp[l * C + k] = s2;
}

// Wcat[k][c] = c<128 ? wp[k][c] : wn[k][c-128]
__global__ void wcat_k(const float* __restrict__ wp, const float* __restrict__ wn,
                       float* __restrict__ wcat) {
    int i = blockIdx.x * blockDim.x + threadIdx.x;
    if (i >= C * 2 * C) return;
    int k = i >> 8, c = i & 255;
    wcat[i] = (c < C) ? wp[k * C + c] : wn[k * C + (c - C)];
}

// ---------------- GEMM: out[N,TC] = A[N,K] @ W[K,TC] (+ epilogue) ----------------
// MODE 0: plain  (xp|xn)
// MODE 1: out = relu(acc + bias[c])                     (lin0)
// MODE 2: out = relu((1-beta)*A[row][c] + beta*acc)     (w1 layer mix; TC==K==lda)
template <int TC, int MODE>
__global__ __launch_bounds__(256) void gemm_k(const float* __restrict__ A, int lda, int K,
                                              int nrows, const float* __restrict__ W,
                                              const float* __restrict__ bias,
                                              float* __restrict__ out, float beta) {
    constexpr int ROWS = 32, KC = 32;
    constexpr int COLT = TC / 4;          // threads along columns
    constexpr int RGRP = 256 / COLT;      // row groups
    constexpr int RPT  = ROWS / RGRP;     // rows per thread
    __shared__ float As[ROWS][KC];
    __shared__ float Ws[KC][TC];
    const int tid = threadIdx.x;
    const int tc = tid % COLT;
    const int tr = tid / COLT;
    const int row0 = blockIdx.x * ROWS;

    float acc[RPT][4];
    #pragma unroll
    for (int r = 0; r < RPT; ++r)
        for (int j = 0; j < 4; ++j) acc[r][j] = 0.f;

    for (int k0 = 0; k0 < K; k0 += KC) {
        int kc = min(KC, K - k0);
        // stage A tile (scalar, guards for edge rows / partial K)
        #pragma unroll
        for (int i = tid; i < ROWS * KC; i += 256) {
            int r = i >> 5, c = i & 31;
            float v = 0.f;
            int gr = row0 + r;
            if (gr < nrows && c < kc) v = A[(size_t)gr * lda + k0 + c];
            As[r][c] = v;
        }
        // stage W tile (float4)
        #pragma unroll
        for (int f = tid * 4; f < KC * TC; f += 1024) {
            int r = f / TC, c = f % TC;
            float4 v = make_float4(0.f, 0.f, 0.f, 0.f);
            if (r < kc) v = *(const float4*)(W + (size_t)(k0 + r) * TC + c);
            *(float4*)&Ws[r][c] = v;
        }
        __syncthreads();
        #pragma unroll
        for (int k = 0; k < KC; k += 4) {
            float4 a4[RPT];
            #pragma unroll
            for (int r = 0; r < RPT; ++r) a4[r] = *(const float4*)&As[tr * RPT + r][k];
            #pragma unroll
            for (int kk = 0; kk < 4; ++kk) {
                float4 wv = *(const float4*)&Ws[k + kk][tc * 4];
                #pragma unroll
                for (int r = 0; r < RPT; ++r) {
                    float a = (kk == 0) ? a4[r].x : (kk == 1) ? a4[r].y : (kk == 2) ? a4[r].z : a4[r].w;
                    acc[r][0] += a * wv.x;
                    acc[r][1] += a * wv.y;
                    acc[r][2] += a * wv.z;
                    acc[r][3] += a * wv.w;
                }
            }
        }
        __syncthreads();
    }
    #pragma unroll
    for (int r = 0; r < RPT; ++r) {
        int row = row0 + tr * RPT + r;
        if (row >= nrows) continue;
        float4 v = make_float4(acc[r][0], acc[r][1], acc[r][2], acc[r][3]);
        if (MODE == 1) {
            float4 b = *(const float4*)(bias + tc * 4);
            v.x = fmaxf(v.x + b.x, 0.f);
            v.y = fmaxf(v.y + b.y, 0.f);
            v.z = fmaxf(v.z + b.z, 0.f);
            v.w = fmaxf(v.w + b.w, 0.f);
        } else if (MODE == 2) {
            float4 hnv = *(const float4*)(A + (size_t)row * lda + tc * 4);
            float ob = 1.f - beta;
            v.x = fmaxf(ob * hnv.x + beta * v.x, 0.f);
            v.y = fmaxf(ob * hnv.y + beta * v.y, 0.f);
            v.z = fmaxf(ob * hnv.z + beta * v.z, 0.f);
            v.w = fmaxf(ob * hnv.w + beta * v.w, 0.f);
        }
        *(float4*)(out + (size_t)row * TC + tc * 4) = v;
    }
}

// sl = h . alp, sr = h . arp  (per node)
__global__ __launch_bounds__(256) void slsr_k(const float* __restrict__ h,
                                              const float* __restrict__ alp,
                                              const float* __restrict__ arp,
                                              float* __restrict__ sl, float* __restrict__ sr,
                                              int n) {
    __shared__ float a[C], b[C];
    if (threadIdx.x < C) { a[threadIdx.x] = alp[threadIdx.x]; b[threadIdx.x] = arp[threadIdx.x]; }
    __syncthreads();
    int i = blockIdx.x * blockDim.x + threadIdx.x;
    if (i >= n) return;
    const float4* hr = (const float4*)(h + (size_t)i * C);
    float s1 = 0.f, s2 = 0.f;
    #pragma unroll 8
    for (int k4 = 0; k4 < C / 4; ++k4) {
        float4 v = hr[k4];
        int k = k4 * 4;
        s1 += v.x * a[k] + v.y * a[k + 1] + v.z * a[k + 2] + v.w * a[k + 3];
        s2 += v.x * b[k] + v.y * b[k + 1] + v.z * b[k + 2] + v.w * b[k + 3];
    }
    sl[i] = s1;
    sr[i] = s2;
}

// per edge: s = sigmoid(leaky_relu(sl[src]+sr[dst])); sigma out; cp = ew*s; cn[dst] += ew*(1-s)
__global__ void edge_k(const int* __restrict__ src, const int* __restrict__ dst,
                       const float* __restrict__ sl, const float* __restrict__ sr,
                       const float* __restrict__ ew, float* __restrict__ cp,
                       float* __restrict__ cn, float* __restrict__ sig_out) {
    int e = blockIdx.x * blockDim.x + threadIdx.x;
    if (e >= EP) return;
    int s, d;
    if (e < NE) { s = src[e]; d = dst[e]; }
    else { s = d = e - NE; }
    float x = sl[s] + sr[d];
    float lr = (x > 0.f) ? x : NEG_SLOPE * x;
    float sg = 1.f / (1.f + expf(-lr));
    sig_out[e] = sg;
    float w = ew[e];
    cp[e] = w * sg;
    atomicAdd(&cn[d], w * (1.f - sg));
}

// one wave per node: agg = sum_{e in CSR[i]} cp[e]*xp[src] + cn[i]*xn[i]; hn = 0.9 agg + 0.1 x0
__global__ __launch_bounds__(256) void agg_k(const int* __restrict__ offs,
                                             const int* __restrict__ csr_src,
                                             const int* __restrict__ csr_eid,
                                             const float* __restrict__ cp,
                                             const float* __restrict__ cn,
                                             const float* __restrict__ xpn,
                                             const float* __restrict__ x0,
                                             float* __restrict__ hn, int n) {
    int wid = (blockIdx.x * blockDim.x + threadIdx.x) >> 6;  // node
    int lane = threadIdx.x & 63;
    if (wid >= n) return;
    int s0 = offs[wid], s1 = offs[wid + 1];
    float2 acc = make_float2(0.f, 0.f);
    for (int j0 = s0; j0 < s1; j0 += 64) {
        int j = j0 + lane;
        int msrc = 0;
        float mcoef = 0.f;
        if (j < s1) { msrc = csr_src[j]; mcoef = cp[csr_eid[j]]; }
        int cnt = min(64, s1 - j0);
        for (int t = 0; t < cnt; ++t) {
            float coef = __shfl(mcoef, t);
            int srcn = __shfl(msrc, t);
            float2 v = ((const float2*)(xpn + (size_t)srcn * 2 * C))[lane];
            acc.x += coef * v.x;
            acc.y += coef * v.y;
        }
    }
    float cni = cn[wid];
    float2 vn = ((const float2*)(xpn + (size_t)wid * 2 * C + C))[lane];
    float2 v0 = ((const float2*)(x0 + (size_t)wid * C))[lane];
    float2 o;
    o.x = (1.f - ALPHA) * (acc.x + cni * vn.x) + ALPHA * v0.x;
    o.y = (1.f - ALPHA) * (acc.y + cni * vn.y) + ALPHA * v0.y;
    ((float2*)(hn + (size_t)wid * C))[lane] = o;
}

// logits + log_softmax
__global__ __launch_bounds__(256) void logits_k(const float* __restrict__ h,
                                                const float* __restrict__ w,
                                                const float* __restrict__ b,
                                                float* __restrict__ out, int n) {
    __shared__ float ws[C * NCLS];
    __shared__ float bs[NCLS];
    for (int i = threadIdx.x; i < C * NCLS; i += 256) ws[i] = w[i];
    if (threadIdx.x < NCLS) bs[threadIdx.x] = b[threadIdx.x];
    __syncthreads();
    int i = blockIdx.x * blockDim.x + threadIdx.x;
    if (i >= n) return;
    const float4* hr = (const float4*)(h + (size_t)i * C);
    float acc[NCLS];
    #pragma unroll
    for (int c = 0; c < NCLS; ++c) acc[c] = 0.f;
    for (int k4 = 0; k4 < C / 4; ++k4) {
        float4 v = hr[k4];
        int k = k4 * 4;
        #pragma unroll
        for (int c = 0; c < NCLS; ++c) {
            acc[c] += v.x * ws[k * NCLS + c] + v.y * ws[(k + 1) * NCLS + c] +
                      v.z * ws[(k + 2) * NCLS + c] + v.w * ws[(k + 3) * NCLS + c];
        }
    }
    float lg[NCLS], m = -1e30f;
    #pragma unroll
    for (int c = 0; c < NCLS; ++c) { lg[c] = acc[c] + bs[c]; m = fmaxf(m, lg[c]); }
    float sum = 0.f;
    #pragma unroll
    for (int c = 0; c < NCLS; ++c) sum += expf(lg[c] - m);
    float lse = m + logf(sum);
    #pragma unroll
    for (int c = 0; c < NCLS; ++c) out[(size_t)i * NCLS + c] = lg[c] - lse;
}

extern "C" void kernel_launch(void* const* d_in, const int* in_sizes, int n_in,
                              void* d_out, int out_size, void* d_ws, size_t ws_size,
                              hipStream_t stream) {
    (void)in_sizes; (void)n_in; (void)out_size; (void)ws_size;
    const float* x      = (const float*)d_in[0];
    const int*   eidx   = (const int*)d_in[1];
    const float* lin0_w = (const float*)d_in[2];
    const float* lin0_b = (const float*)d_in[3];
    const float* lin1_w = (const float*)d_in[4];
    const float* lin1_b = (const float*)d_in[5];
    const float* lin_w  = (const float*)d_in[6];
    const float* att_l  = (const float*)d_in[7];
    const float* att_r  = (const float*)d_in[8];
    const float* w_p    = (const float*)d_in[9];
    const float* w_n    = (const float*)d_in[10];
    const float* w1     = (const float*)d_in[11];
    float* outp = (float*)d_out;
    float* sig_base = outp + (size_t)NN * NCLS;   // sigmas [L, EP]

    const int* srcA = eidx;
    const int* dstA = eidx + NE;

    // workspace carve-up
    float* f = (float*)d_ws;
    float* x0   = f; f += (size_t)NN * C;
    float* hA   = f; f += (size_t)NN * C;
    float* hB   = f; f += (size_t)NN * C;
    float* hn   = f; f += (size_t)NN * C;
    float* xpn  = f; f += (size_t)NN * 2 * C;
    float* sl   = f; f += NN;
    float* sr   = f; f += NN;
    float* cp   = f; f += EP;
    float* ew   = f; f += EP;
    float* cn   = f; f += NN;
    float* dinv = f; f += NN;
    float* alp  = f; f += NL * C;
    float* arp  = f; f += NL * C;
    float* wcat = f; f += C * 2 * C;
    int* ip = (int*)f;
    int* deg     = ip; ip += NN;
    int* offs    = ip; ip += NN + 4;
    int* cursor  = ip; ip += NN;
    int* csr_src = ip; ip += EP;
    int* csr_eid = ip; ip += EP;

    dim3 B(256);
    int gN   = (NN + 255) / 256;
    int gE   = (NE + 255) / 256;
    int gEP  = (EP + 255) / 256;
    int gGemm = (NN + 31) / 32;
    int gAgg = NN / 4;  // one wave (64 lanes) per node, 4 waves/block

    // ---- graph prep ----
    fill_i32_k<<<gN, B, 0, stream>>>(deg, 1, NN);  // self-loop counts
    count_deg_k<<<gE, B, 0, stream>>>(dstA, deg, NE);
    dinv_k<<<gN, B, 0, stream>>>(deg, dinv, NN);
    scan_k<<<1, 1024, 0, stream>>>(deg, offs, cursor, NN);
    ew_k<<<gEP, B, 0, stream>>>(srcA, dstA, dinv, ew);
    csr_fill_k<<<gEP, B, 0, stream>>>(srcA, dstA, cursor, csr_src, csr_eid);
    attproj_k<<<NL, C, 0, stream>>>(lin_w, att_l, att_r, alp, arp);

    // ---- x0 = relu(x @ lin0_w + b) ----
    gemm_k<C, 1><<<gGemm, B, 0, stream>>>(x, FIN, FIN, NN, lin0_w, lin0_b, x0, 0.f);

    // ---- layers ----
    const float* cur = x0;
    for (int l = 0; l < NL; ++l) {
        float beta = (float)log(0.5 / (double)(l + 1) + 1.0);
        float* nxt = (l & 1) ? hB : hA;
        wcat_k<<<(C * 2 * C + 255) / 256, B, 0, stream>>>(w_p + (size_t)l * C * C,
                                                          w_n + (size_t)l * C * C, wcat);
        gemm_k<2 * C, 0><<<gGemm, B, 0, stream>>>(cur, C, C, NN, wcat, nullptr, xpn, 0.f);
        slsr_k<<<gN, B, 0, stream>>>(cur, alp + l * C, arp + l * C, sl, sr, NN);
        fill_f32_k<<<gN, B, 0, stream>>>(cn, 0.f, NN);
        edge_k<<<gEP, B, 0, stream>>>(srcA, dstA, sl, sr, ew, cp, cn,
                                      sig_base + (size_t)l * EP);
        agg_k<<<gAgg, B, 0, stream>>>(offs, csr_src, csr_eid, cp, cn, xpn, x0, hn, NN);
        gemm_k<C, 2><<<gGemm, B, 0, stream>>>(hn, C, C, NN, w1 + (size_t)l * C * C, nullptr,
                                              nxt, beta);
        cur = nxt;
    }

    // ---- logits + log_softmax ----
    logits_k<<<gN, B, 0, stream>>>(cur, lin1_w, lin1_b, outp, NN);
}

// Round 2
// 1802.563 us; speedup vs baseline: 1.3910x; 1.3910x over previous
//
#include <hip/hip_runtime.h>
#include <math.h>

// Problem constants
constexpr int NN   = 50000;          // nodes
constexpr int NE   = 800000;         // edges (without self loops)
constexpr int EP   = NE + NN;        // edges + self loops = 850000
constexpr int FIN  = 500;
constexpr int KPAD = 512;            // lin0 K padded
constexpr int C    = 128;
constexpr int NCLS = 7;
constexpr int NL   = 8;
constexpr float ALPHA = 0.1f;
constexpr float NEG_SLOPE = 0.2f;

typedef __bf16 bf16;
typedef __bf16 bf16x8 __attribute__((ext_vector_type(8)));
typedef float  f32x4  __attribute__((ext_vector_type(4)));

__device__ inline unsigned short f2bu(float f) {
    bf16 b = (bf16)f;
    return __builtin_bit_cast(unsigned short, b);
}

// ---------------- utility fills ----------------
__global__ void fill_i32_k(int* p, int v, int n) {
    int i = blockIdx.x * blockDim.x + threadIdx.x;
    if (i < n) p[i] = v;
}
__global__ void fill_f32_k(float* p, float v, int n) {
    int i = blockIdx.x * blockDim.x + threadIdx.x;
    if (i < n) p[i] = v;
}

// ---------------- graph prep ----------------
__global__ void count_deg_k(const int* __restrict__ dst, int* __restrict__ deg, int e) {
    int i = blockIdx.x * blockDim.x + threadIdx.x;
    if (i < e) atomicAdd(&deg[dst[i]], 1);
}

__global__ void dinv_k(const int* __restrict__ deg, float* __restrict__ dinv, int n) {
    int i = blockIdx.x * blockDim.x + threadIdx.x;
    if (i < n) dinv[i] = rsqrtf((float)deg[i]);
}

__global__ __launch_bounds__(1024) void scan_k(const int* __restrict__ deg,
                                               int* __restrict__ offs,
                                               int* __restrict__ cursor, int n) {
    __shared__ int sums[1024];
    int t = threadIdx.x;
    int chunk = (n + 1023) >> 10;
    int base = t * chunk;
    int s = 0;
    for (int j = 0; j < chunk; ++j) {
        int i = base + j;
        if (i < n) s += deg[i];
    }
    sums[t] = s;
    __syncthreads();
    for (int off = 1; off < 1024; off <<= 1) {
        int v = (t >= off) ? sums[t - off] : 0;
        __syncthreads();
        sums[t] += v;
        __syncthreads();
    }
    int run = (t == 0) ? 0 : sums[t - 1];
    for (int j = 0; j < chunk; ++j) {
        int i = base + j;
        if (i < n) { offs[i] = run; cursor[i] = run; run += deg[i]; }
    }
    if (t == 0) offs[n] = sums[1023];
}

__global__ void ew_k(const int* __restrict__ src, const int* __restrict__ dst,
                     const float* __restrict__ dinv, float* __restrict__ ew) {
    int e = blockIdx.x * blockDim.x + threadIdx.x;
    if (e >= EP) return;
    if (e < NE) ew[e] = dinv[src[e]] * dinv[dst[e]];
    else { float d = dinv[e - NE]; ew[e] = d * d; }
}

__global__ void csr_fill_k(const int* __restrict__ src, const int* __restrict__ dst,
                           int* __restrict__ cursor, int* __restrict__ csr_src,
                           int* __restrict__ csr_eid) {
    int e = blockIdx.x * blockDim.x + threadIdx.x;
    if (e >= EP) return;
    int s, d;
    if (e < NE) { s = src[e]; d = dst[e]; }
    else { s = d = e - NE; }
    int pos = atomicAdd(&cursor[d], 1);
    csr_src[pos] = s;
    csr_eid[pos] = e;
}

// alp[l] = lin_w[l] @ att_l[l]; arp[l] = lin_w[l] @ att_r[l]  (fp32, exact path to sigma)
__global__ void attproj_k(const float* __restrict__ lin_w, const float* __restrict__ att_l,
                          const float* __restrict__ att_r, float* __restrict__ alp,
                          float* __restrict__ arp) {
    __shared__ float al[C], ar[C];
    int l = blockIdx.x;
    int k = threadIdx.x;
    al[k] = att_l[l * C + k];
    ar[k] = att_r[l * C + k];
    __syncthreads();
    const float* w = lin_w + (size_t)l * C * C + (size_t)k * C;
    float s1 = 0.f, s2 = 0.f;
    #pragma unroll 8
    for (int c = 0; c < C; ++c) { float v = w[c]; s1 += v * al[c]; s2 += v * ar[c]; }
    alp[l * C + k] = s1;
    arp[l * C + k] = s2;
}

// ---------------- weight pre-pack into MFMA B-fragment layout ----------------
// Layout: frag index ((nt*KB + kb)*64 + lane)*8 + j  holds  W[kb*32 + (lane>>4)*8 + j][nt*16 + (lane&15)]
// xp|xn concat: nt 0..7 from w_p, nt 8..15 from w_n (per layer)
__global__ void wpn_trans_k(const float* __restrict__ w_p, const float* __restrict__ w_n,
                            bf16* __restrict__ out) {
    int l = blockIdx.y;
    int nt = blockIdx.x >> 2, kb = blockIdx.x & 3;   // NT=16, KB=4
    int lane = threadIdx.x;
    const float* W = ((nt < 8) ? w_p : w_n) + (size_t)l * C * C;
    int col = (nt & 7) * 16 + (lane & 15);
    int k0 = kb * 32 + (lane >> 4) * 8;
    bf16* o = out + (((size_t)l * 16 * 4 + (size_t)(nt * 4 + kb)) * 64 + lane) * 8;
    #pragma unroll
    for (int j = 0; j < 8; ++j) o[j] = (bf16)W[(size_t)(k0 + j) * C + col];
}

__global__ void w1_trans_k(const float* __restrict__ w1, bf16* __restrict__ out) {
    int l = blockIdx.y;
    int nt = blockIdx.x >> 2, kb = blockIdx.x & 3;   // NT=8, KB=4
    int lane = threadIdx.x;
    const float* W = w1 + (size_t)l * C * C;
    int col = nt * 16 + (lane & 15);
    int k0 = kb * 32 + (lane >> 4) * 8;
    bf16* o = out + (((size_t)l * 8 * 4 + (size_t)(nt * 4 + kb)) * 64 + lane) * 8;
    #pragma unroll
    for (int j = 0; j < 8; ++j) o[j] = (bf16)W[(size_t)(k0 + j) * C + col];
}

__global__ void lin0_trans_k(const float* __restrict__ w, bf16* __restrict__ out) {
    int nt = blockIdx.x >> 4, kb = blockIdx.x & 15;  // NT=8, KB=16 (K padded to 512)
    int lane = threadIdx.x;
    int col = nt * 16 + (lane & 15);
    int k0 = kb * 32 + (lane >> 4) * 8;
    bf16* o = out + (((size_t)(nt * 16 + kb)) * 64 + lane) * 8;
    #pragma unroll
    for (int j = 0; j < 8; ++j) {
        int k = k0 + j;
        o[j] = (bf16)((k < FIN) ? w[(size_t)k * C + col] : 0.f);
    }
}

// x [N,500] fp32 -> xb [N,512] bf16 (zero-padded)
__global__ void conv_x_k(const float* __restrict__ x, bf16* __restrict__ xb) {
    int i = blockIdx.x * blockDim.x + threadIdx.x;
    if (i >= NN * KPAD) return;
    int row = i >> 9, col = i & (KPAD - 1);
    float v = (col < FIN) ? x[(size_t)row * FIN + col] : 0.f;
    xb[i] = (bf16)v;
}

// ---------------- MFMA GEMM: out[M, NT*16] = Ab[M, KB*32] @ W ----------------
// MODE 0: bf16 store only (xp|xn)
// MODE 1: v = relu(acc + bias[col]); store fp32 + bf16         (lin0 -> x0, x0b)
// MODE 2: v = relu((1-beta)*hn_f + beta*acc); store fp32+bf16  (w1 mix -> h, hb)
template <int NT, int KB, int MODE>
__global__ __launch_bounds__(256) void mgemm_k(const bf16* __restrict__ Ab,
                                               const bf16* __restrict__ Wt, int M,
                                               const float* __restrict__ bias,
                                               const float* __restrict__ hn_f, float beta,
                                               float* __restrict__ out_f,
                                               bf16* __restrict__ out_b) {
    const int lane = threadIdx.x & 63;
    const int wv = threadIdx.x >> 6;
    const int m0 = blockIdx.x * 64 + wv * 16;
    const int mrow = lane & 15;
    const int quad = lane >> 4;
    int arow = m0 + mrow;
    if (arow >= M) arow = M - 1;
    const bf16* Arow = Ab + (size_t)arow * (KB * 32) + quad * 8;
    const bf16x8* wbase = reinterpret_cast<const bf16x8*>(Wt) + (size_t)lane;

    f32x4 acc[NT];
    #pragma unroll
    for (int t = 0; t < NT; ++t) acc[t] = (f32x4){0.f, 0.f, 0.f, 0.f};

    #pragma unroll
    for (int kb = 0; kb < KB; ++kb) {
        bf16x8 a = *reinterpret_cast<const bf16x8*>(Arow + kb * 32);
        #pragma unroll
        for (int t = 0; t < NT; ++t) {
            bf16x8 b = wbase[(size_t)(t * KB + kb) * 64];
            acc[t] = __builtin_amdgcn_mfma_f32_16x16x32_bf16(a, b, acc[t], 0, 0, 0);
        }
    }

    constexpr int NC = NT * 16;
    #pragma unroll
    for (int t = 0; t < NT; ++t) {
        int col = t * 16 + mrow;
        #pragma unroll
        for (int r = 0; r < 4; ++r) {
            int row = m0 + quad * 4 + r;
            if (row >= M) continue;
            float v = acc[t][r];
            if (MODE == 1) v = fmaxf(v + bias[col], 0.f);
            if (MODE == 2) {
                float h = hn_f[(size_t)row * NC + col];
                v = fmaxf((1.f - beta) * h + beta * v, 0.f);
            }
            if (MODE != 0) out_f[(size_t)row * NC + col] = v;
            out_b[(size_t)row * NC + col] = (bf16)v;
        }
    }
}

// sl = h . alp, sr = h . arp  (fp32 — feeds sigma output, keep precise)
__global__ __launch_bounds__(256) void slsr_k(const float* __restrict__ h,
                                              const float* __restrict__ alp,
                                              const float* __restrict__ arp,
                                              float* __restrict__ sl, float* __restrict__ sr,
                                              int n) {
    __shared__ float a[C], b[C];
    if (threadIdx.x < C) { a[threadIdx.x] = alp[threadIdx.x]; b[threadIdx.x] = arp[threadIdx.x]; }
    __syncthreads();
    int i = blockIdx.x * blockDim.x + threadIdx.x;
    if (i >= n) return;
    const float4* hr = (const float4*)(h + (size_t)i * C);
    float s1 = 0.f, s2 = 0.f;
    #pragma unroll 8
    for (int k4 = 0; k4 < C / 4; ++k4) {
        float4 v = hr[k4];
        int k = k4 * 4;
        s1 += v.x * a[k] + v.y * a[k + 1] + v.z * a[k + 2] + v.w * a[k + 3];
        s2 += v.x * b[k] + v.y * b[k + 1] + v.z * b[k + 2] + v.w * b[k + 3];
    }
    sl[i] = s1;
    sr[i] = s2;
}

// per edge: s = sigmoid(leaky_relu(sl[src]+sr[dst])); cp = ew*s; cn[dst] += ew*(1-s)
__global__ void edge_k(const int* __restrict__ src, const int* __restrict__ dst,
                       const float* __restrict__ sl, const float* __restrict__ sr,
                       const float* __restrict__ ew, float* __restrict__ cp,
                       float* __restrict__ cn, float* __restrict__ sig_out) {
    int e = blockIdx.x * blockDim.x + threadIdx.x;
    if (e >= EP) return;
    int s, d;
    if (e < NE) { s = src[e]; d = dst[e]; }
    else { s = d = e - NE; }
    float x = sl[s] + sr[d];
    float lr = (x > 0.f) ? x : NEG_SLOPE * x;
    float sg = 1.f / (1.f + expf(-lr));
    sig_out[e] = sg;
    float w = ew[e];
    cp[e] = w * sg;
    atomicAdd(&cn[d], w * (1.f - sg));
}

// one wave per node: agg = sum cp[e]*xp_b[src] + cn[i]*xn_b[i]; hn = 0.9*agg + 0.1*x0
// xpn_b rows: 256 bf16 = [xp(128) | xn(128)]
__global__ __launch_bounds__(256) void agg_k(const int* __restrict__ offs,
                                             const int* __restrict__ csr_src,
                                             const int* __restrict__ csr_eid,
                                             const float* __restrict__ cp,
                                             const float* __restrict__ cn,
                                             const bf16* __restrict__ xpnb,
                                             const float* __restrict__ x0,
                                             float* __restrict__ hn,
                                             bf16* __restrict__ hnb, int n) {
    int wid = (blockIdx.x * blockDim.x + threadIdx.x) >> 6;  // node
    int lane = threadIdx.x & 63;
    if (wid >= n) return;
    int s0 = offs[wid], s1 = offs[wid + 1];
    float ax = 0.f, ay = 0.f;
    for (int j0 = s0; j0 < s1; j0 += 64) {
        int j = j0 + lane;
        int msrc = 0;
        float mcoef = 0.f;
        if (j < s1) { msrc = csr_src[j]; mcoef = cp[csr_eid[j]]; }
        int cnt = min(64, s1 - j0);
        for (int t = 0; t < cnt; ++t) {
            float coef = __shfl(mcoef, t);
            int srcn = __shfl(msrc, t);
            unsigned u = ((const unsigned*)(xpnb + (size_t)srcn * 2 * C))[lane];
            float lo = __builtin_bit_cast(float, u << 16);
            float hi = __builtin_bit_cast(float, u & 0xffff0000u);
            ax += coef * lo;
            ay += coef * hi;
        }
    }
    float cni = cn[wid];
    unsigned un = ((const unsigned*)(xpnb + (size_t)wid * 2 * C))[64 + lane];
    float nlo = __builtin_bit_cast(float, un << 16);
    float nhi = __builtin_bit_cast(float, un & 0xffff0000u);
    float2 v0 = ((const float2*)(x0 + (size_t)wid * C))[lane];
    float ox = (1.f - ALPHA) * (ax + cni * nlo) + ALPHA * v0.x;
    float oy = (1.f - ALPHA) * (ay + cni * nhi) + ALPHA * v0.y;
    ((float2*)(hn + (size_t)wid * C))[lane] = make_float2(ox, oy);
    unsigned pk = (unsigned)f2bu(ox) | ((unsigned)f2bu(oy) << 16);
    ((unsigned*)(hnb + (size_t)wid * C))[lane] = pk;
}

// logits + log_softmax (fp32)
__global__ __launch_bounds__(256) void logits_k(const float* __restrict__ h,
                                                const float* __restrict__ w,
                                                const float* __restrict__ b,
                                                float* __restrict__ out, int n) {
    __shared__ float ws[C * NCLS];
    __shared__ float bs[NCLS];
    for (int i = threadIdx.x; i < C * NCLS; i += 256) ws[i] = w[i];
    if (threadIdx.x < NCLS) bs[threadIdx.x] = b[threadIdx.x];
    __syncthreads();
    int i = blockIdx.x * blockDim.x + threadIdx.x;
    if (i >= n) return;
    const float4* hr = (const float4*)(h + (size_t)i * C);
    float acc[NCLS];
    #pragma unroll
    for (int c = 0; c < NCLS; ++c) acc[c] = 0.f;
    for (int k4 = 0; k4 < C / 4; ++k4) {
        float4 v = hr[k4];
        int k = k4 * 4;
        #pragma unroll
        for (int c = 0; c < NCLS; ++c) {
            acc[c] += v.x * ws[k * NCLS + c] + v.y * ws[(k + 1) * NCLS + c] +
                      v.z * ws[(k + 2) * NCLS + c] + v.w * ws[(k + 3) * NCLS + c];
        }
    }
    float lg[NCLS], m = -1e30f;
    #pragma unroll
    for (int c = 0; c < NCLS; ++c) { lg[c] = acc[c] + bs[c]; m = fmaxf(m, lg[c]); }
    float sum = 0.f;
    #pragma unroll
    for (int c = 0; c < NCLS; ++c) sum += expf(lg[c] - m);
    float lse = m + logf(sum);
    #pragma unroll
    for (int c = 0; c < NCLS; ++c) out[(size_t)i * NCLS + c] = lg[c] - lse;
}

extern "C" void kernel_launch(void* const* d_in, const int* in_sizes, int n_in,
                              void* d_out, int out_size, void* d_ws, size_t ws_size,
                              hipStream_t stream) {
    (void)in_sizes; (void)n_in; (void)out_size; (void)ws_size;
    const float* x      = (const float*)d_in[0];
    const int*   eidx   = (const int*)d_in[1];
    const float* lin0_w = (const float*)d_in[2];
    const float* lin0_b = (const float*)d_in[3];
    const float* lin1_w = (const float*)d_in[4];
    const float* lin1_b = (const float*)d_in[5];
    const float* lin_w  = (const float*)d_in[6];
    const float* att_l  = (const float*)d_in[7];
    const float* att_r  = (const float*)d_in[8];
    const float* w_p    = (const float*)d_in[9];
    const float* w_n    = (const float*)d_in[10];
    const float* w1     = (const float*)d_in[11];
    float* outp = (float*)d_out;
    float* sig_base = outp + (size_t)NN * NCLS;   // sigmas [L, EP]

    const int* srcA = eidx;
    const int* dstA = eidx + NE;

    // ---------------- workspace carve-up ----------------
    float* f = (float*)d_ws;
    float* x0   = f; f += (size_t)NN * C;        // 6.4M
    float* hF   = f; f += (size_t)NN * C;        // 6.4M (single fp32 h buffer)
    float* hn   = f; f += (size_t)NN * C;        // 6.4M
    float* sl   = f; f += NN;
    float* sr   = f; f += NN;
    float* cp   = f; f += EP;
    float* ew   = f; f += EP;
    float* cn   = f; f += NN;
    float* dinv = f; f += NN;
    float* alp  = f; f += NL * C;
    float* arp  = f; f += NL * C;
    // bf16 region (16B aligned: all preceding counts are multiples of 4 floats)
    bf16* bp = (bf16*)f;
    // union region: xb [NN*512] overlays [xpnb | hnb | hb] (xb dead after lin0 GEMM)
    bf16* xb    = bp;
    bf16* xpnb  = bp;  bp += (size_t)NN * 2 * C;   // 12.8M elems
    bf16* hnb   = bp;  bp += (size_t)NN * C;       // 6.4M
    bf16* hb    = bp;  bp += (size_t)NN * C;       // 6.4M  (== xb end: NN*512)
    bf16* x0b   = bp;  bp += (size_t)NN * C;
    bf16* wpnt  = bp;  bp += (size_t)NL * 16 * 4 * 64 * 8;   // 262144
    bf16* w1t   = bp;  bp += (size_t)NL * 8 * 4 * 64 * 8;    // 131072
    bf16* lin0t = bp;  bp += (size_t)8 * 16 * 64 * 8;        // 65536
    int* ip = (int*)bp;
    int* deg     = ip; ip += NN;
    int* offs    = ip; ip += NN + 4;
    int* cursor  = ip; ip += NN;
    int* csr_src = ip; ip += EP;
    int* csr_eid = ip; ip += EP;

    dim3 B(256);
    int gN   = (NN + 255) / 256;
    int gE   = (NE + 255) / 256;
    int gEP  = (EP + 255) / 256;
    int gM64 = (NN + 63) / 64;       // 782 blocks for MFMA GEMMs
    int gAgg = NN / 4;               // one wave per node

    // ---- graph prep ----
    fill_i32_k<<<gN, B, 0, stream>>>(deg, 1, NN);
    count_deg_k<<<gE, B, 0, stream>>>(dstA, deg, NE);
    dinv_k<<<gN, B, 0, stream>>>(deg, dinv, NN);
    scan_k<<<1, 1024, 0, stream>>>(deg, offs, cursor, NN);
    ew_k<<<gEP, B, 0, stream>>>(srcA, dstA, dinv, ew);
    csr_fill_k<<<gEP, B, 0, stream>>>(srcA, dstA, cursor, csr_src, csr_eid);
    attproj_k<<<NL, C, 0, stream>>>(lin_w, att_l, att_r, alp, arp);

    // ---- weight packs + input conversion ----
    wpn_trans_k<<<dim3(64, NL), 64, 0, stream>>>(w_p, w_n, wpnt);
    w1_trans_k<<<dim3(32, NL), 64, 0, stream>>>(w1, w1t);
    lin0_trans_k<<<128, 64, 0, stream>>>(lin0_w, lin0t);
    conv_x_k<<<(NN * KPAD + 255) / 256, B, 0, stream>>>(x, xb);

    // ---- x0 = relu(x @ lin0_w + b) ----
    mgemm_k<8, 16, 1><<<gM64, B, 0, stream>>>(xb, lin0t, NN, lin0_b, nullptr, 0.f, x0, x0b);

    // ---- layers ----
    const float* cur = x0;
    const bf16* curb = x0b;
    for (int l = 0; l < NL; ++l) {
        float beta = (float)log(0.5 / (double)(l + 1) + 1.0);
        // xp|xn = h @ [wp|wn]  (bf16 MFMA, bf16 out)
        mgemm_k<16, 4, 0><<<gM64, B, 0, stream>>>(curb, wpnt + (size_t)l * 16 * 4 * 64 * 8,
                                                  NN, nullptr, nullptr, 0.f, nullptr, xpnb);
        slsr_k<<<gN, B, 0, stream>>>(cur, alp + l * C, arp + l * C, sl, sr, NN);
        fill_f32_k<<<gN, B, 0, stream>>>(cn, 0.f, NN);
        edge_k<<<gEP, B, 0, stream>>>(srcA, dstA, sl, sr, ew, cp, cn,
                                      sig_base + (size_t)l * EP);
        agg_k<<<gAgg, B, 0, stream>>>(offs, csr_src, csr_eid, cp, cn, xpnb, x0, hn, hnb, NN);
        // h = relu((1-beta)*hn + beta*(hn @ w1))
        mgemm_k<8, 4, 2><<<gM64, B, 0, stream>>>(hnb, w1t + (size_t)l * 8 * 4 * 64 * 8,
                                                 NN, nullptr, hn, beta, hF, hb);
        cur = hF;
        curb = hb;
    }

    // ---- logits + log_softmax ----
    logits_k<<<gN, B, 0, stream>>>(cur, lin1_w, lin1_b, outp, NN);
}

// Round 3
// 1512.327 us; speedup vs baseline: 1.6579x; 1.1919x over previous
//
#include <hip/hip_runtime.h>
#include <math.h>

// Problem constants
constexpr int NN   = 50000;          // nodes
constexpr int NE   = 800000;         // edges (without self loops)
constexpr int EP   = NE + NN;        // edges + self loops = 850000
constexpr int FIN  = 500;
constexpr int KPAD = 512;            // lin0 K padded
constexpr int C    = 128;
constexpr int NCLS = 7;
constexpr int NL   = 8;
constexpr float ALPHA = 0.1f;
constexpr float NEG_SLOPE = 0.2f;

typedef __bf16 bf16;
typedef __bf16 bf16x8 __attribute__((ext_vector_type(8)));
typedef float  f32x4  __attribute__((ext_vector_type(4)));

__device__ inline unsigned short f2bu(float f) {
    bf16 b = (bf16)f;
    return __builtin_bit_cast(unsigned short, b);
}
__device__ inline float bulo(unsigned u) { return __builtin_bit_cast(float, u << 16); }
__device__ inline float buhi(unsigned u) { return __builtin_bit_cast(float, u & 0xffff0000u); }

// ---------------- utility fills ----------------
__global__ void fill_i32_k(int* p, int v, int n) {
    int i = blockIdx.x * blockDim.x + threadIdx.x;
    if (i < n) p[i] = v;
}
__global__ void fill_f32_k(float* p, float v, int n) {
    int i = blockIdx.x * blockDim.x + threadIdx.x;
    if (i < n) p[i] = v;
}

// ---------------- graph prep ----------------
__global__ void count_deg_k(const int* __restrict__ dst, int* __restrict__ deg, int e) {
    int i = blockIdx.x * blockDim.x + threadIdx.x;
    if (i < e) atomicAdd(&deg[dst[i]], 1);
}

__global__ void dinv_k(const int* __restrict__ deg, float* __restrict__ dinv, int n) {
    int i = blockIdx.x * blockDim.x + threadIdx.x;
    if (i < n) dinv[i] = rsqrtf((float)deg[i]);
}

// ---- 3-pass scan: per-block LDS scan -> scan of block sums -> add offsets ----
constexpr int SCB = 256;                       // scan block size
constexpr int NSB = (NN + SCB - 1) / SCB;      // 196 blocks

__global__ __launch_bounds__(SCB) void scan1_k(const int* __restrict__ deg,
                                               int* __restrict__ exoff,
                                               int* __restrict__ bsum, int n) {
    __shared__ int s[SCB];
    int t = threadIdx.x;
    int i = blockIdx.x * SCB + t;
    int v = (i < n) ? deg[i] : 0;
    s[t] = v;
    __syncthreads();
    for (int off = 1; off < SCB; off <<= 1) {
        int u = (t >= off) ? s[t - off] : 0;
        __syncthreads();
        s[t] += u;
        __syncthreads();
    }
    if (i < n) exoff[i] = s[t] - v;           // exclusive within block
    if (t == SCB - 1) bsum[blockIdx.x] = s[t];
}

__global__ __launch_bounds__(SCB) void scan2_k(const int* __restrict__ bsum,
                                               int* __restrict__ boff, int nb) {
    __shared__ int s[SCB];
    int t = threadIdx.x;
    int v = (t < nb) ? bsum[t] : 0;
    s[t] = v;
    __syncthreads();
    for (int off = 1; off < SCB; off <<= 1) {
        int u = (t >= off) ? s[t - off] : 0;
        __syncthreads();
        s[t] += u;
        __syncthreads();
    }
    if (t < nb) boff[t] = s[t] - v;
}

__global__ __launch_bounds__(SCB) void scan3_k(const int* __restrict__ exoff,
                                               const int* __restrict__ boff,
                                               int* __restrict__ offs,
                                               int* __restrict__ cursor, int n) {
    int i = blockIdx.x * SCB + threadIdx.x;
    if (i < n) {
        int o = exoff[i] + boff[blockIdx.x];
        offs[i] = o;
        cursor[i] = o;
    }
    if (i == 0) offs[n] = EP;
}

__global__ void ew_k(const int* __restrict__ src, const int* __restrict__ dst,
                     const float* __restrict__ dinv, float* __restrict__ ew) {
    int e = blockIdx.x * blockDim.x + threadIdx.x;
    if (e >= EP) return;
    if (e < NE) ew[e] = dinv[src[e]] * dinv[dst[e]];
    else { float d = dinv[e - NE]; ew[e] = d * d; }
}

__global__ void csr_fill_k(const int* __restrict__ src, const int* __restrict__ dst,
                           int* __restrict__ cursor, int* __restrict__ csr_src,
                           int* __restrict__ pos_of) {
    int e = blockIdx.x * blockDim.x + threadIdx.x;
    if (e >= EP) return;
    int s, d;
    if (e < NE) { s = src[e]; d = dst[e]; }
    else { s = d = e - NE; }
    int pos = atomicAdd(&cursor[d], 1);
    csr_src[pos] = s;
    pos_of[e] = pos;
}

// alp[l] = lin_w[l] @ att_l[l]; arp[l] = lin_w[l] @ att_r[l]  (fp32, exact path to sigma)
__global__ void attproj_k(const float* __restrict__ lin_w, const float* __restrict__ att_l,
                          const float* __restrict__ att_r, float* __restrict__ alp,
                          float* __restrict__ arp) {
    __shared__ float al[C], ar[C];
    int l = blockIdx.x;
    int k = threadIdx.x;
    al[k] = att_l[l * C + k];
    ar[k] = att_r[l * C + k];
    __syncthreads();
    const float* w = lin_w + (size_t)l * C * C + (size_t)k * C;
    float s1 = 0.f, s2 = 0.f;
    #pragma unroll 8
    for (int c = 0; c < C; ++c) { float v = w[c]; s1 += v * al[c]; s2 += v * ar[c]; }
    alp[l * C + k] = s1;
    arp[l * C + k] = s2;
}

// ---------------- weight pre-pack into MFMA B-fragment layout ----------------
__global__ void wpn_trans_k(const float* __restrict__ w_p, const float* __restrict__ w_n,
                            bf16* __restrict__ out) {
    int l = blockIdx.y;
    int nt = blockIdx.x >> 2, kb = blockIdx.x & 3;   // NT=16, KB=4
    int lane = threadIdx.x;
    const float* W = ((nt < 8) ? w_p : w_n) + (size_t)l * C * C;
    int col = (nt & 7) * 16 + (lane & 15);
    int k0 = kb * 32 + (lane >> 4) * 8;
    bf16* o = out + (((size_t)l * 16 * 4 + (size_t)(nt * 4 + kb)) * 64 + lane) * 8;
    #pragma unroll
    for (int j = 0; j < 8; ++j) o[j] = (bf16)W[(size_t)(k0 + j) * C + col];
}

__global__ void w1_trans_k(const float* __restrict__ w1, bf16* __restrict__ out) {
    int l = blockIdx.y;
    int nt = blockIdx.x >> 2, kb = blockIdx.x & 3;   // NT=8, KB=4
    int lane = threadIdx.x;
    const float* W = w1 + (size_t)l * C * C;
    int col = nt * 16 + (lane & 15);
    int k0 = kb * 32 + (lane >> 4) * 8;
    bf16* o = out + (((size_t)l * 8 * 4 + (size_t)(nt * 4 + kb)) * 64 + lane) * 8;
    #pragma unroll
    for (int j = 0; j < 8; ++j) o[j] = (bf16)W[(size_t)(k0 + j) * C + col];
}

__global__ void lin0_trans_k(const float* __restrict__ w, bf16* __restrict__ out) {
    int nt = blockIdx.x >> 4, kb = blockIdx.x & 15;  // NT=8, KB=16 (K padded to 512)
    int lane = threadIdx.x;
    int col = nt * 16 + (lane & 15);
    int k0 = kb * 32 + (lane >> 4) * 8;
    bf16* o = out + (((size_t)(nt * 16 + kb)) * 64 + lane) * 8;
    #pragma unroll
    for (int j = 0; j < 8; ++j) {
        int k = k0 + j;
        o[j] = (bf16)((k < FIN) ? w[(size_t)k * C + col] : 0.f);
    }
}

// x [N,500] fp32 -> xb [N,512] bf16 (zero-padded)
__global__ void conv_x_k(const float* __restrict__ x, bf16* __restrict__ xb) {
    int i = blockIdx.x * blockDim.x + threadIdx.x;
    if (i >= NN * KPAD) return;
    int row = i >> 9, col = i & (KPAD - 1);
    float v = (col < FIN) ? x[(size_t)row * FIN + col] : 0.f;
    xb[i] = (bf16)v;
}

// ---------------- MFMA GEMM: out[M, NT*16] = Ab[M, KB*32] @ W ----------------
// MODE 0: bf16 store only (xp|xn)
// MODE 1: v = relu(acc + bias[col]); store fp32 + bf16         (lin0 -> x0, x0b)
// MODE 2: v = relu((1-beta)*hn_f + beta*acc); store fp32+bf16  (w1 mix -> h, hb)
template <int NT, int KB, int MODE>
__global__ __launch_bounds__(256) void mgemm_k(const bf16* __restrict__ Ab,
                                               const bf16* __restrict__ Wt, int M,
                                               const float* __restrict__ bias,
                                               const float* __restrict__ hn_f, float beta,
                                               float* __restrict__ out_f,
                                               bf16* __restrict__ out_b) {
    const int lane = threadIdx.x & 63;
    const int wv = threadIdx.x >> 6;
    const int m0 = blockIdx.x * 64 + wv * 16;
    const int mrow = lane & 15;
    const int quad = lane >> 4;
    int arow = m0 + mrow;
    if (arow >= M) arow = M - 1;
    const bf16* Arow = Ab + (size_t)arow * (KB * 32) + quad * 8;
    const bf16x8* wbase = reinterpret_cast<const bf16x8*>(Wt) + (size_t)lane;

    f32x4 acc[NT];
    #pragma unroll
    for (int t = 0; t < NT; ++t) acc[t] = (f32x4){0.f, 0.f, 0.f, 0.f};

    #pragma unroll
    for (int kb = 0; kb < KB; ++kb) {
        bf16x8 a = *reinterpret_cast<const bf16x8*>(Arow + kb * 32);
        #pragma unroll
        for (int t = 0; t < NT; ++t) {
            bf16x8 b = wbase[(size_t)(t * KB + kb) * 64];
            acc[t] = __builtin_amdgcn_mfma_f32_16x16x32_bf16(a, b, acc[t], 0, 0, 0);
        }
    }

    constexpr int NC = NT * 16;
    #pragma unroll
    for (int t = 0; t < NT; ++t) {
        int col = t * 16 + mrow;
        #pragma unroll
        for (int r = 0; r < 4; ++r) {
            int row = m0 + quad * 4 + r;
            if (row >= M) continue;
            float v = acc[t][r];
            if (MODE == 1) v = fmaxf(v + bias[col], 0.f);
            if (MODE == 2) {
                float h = hn_f[(size_t)row * NC + col];
                v = fmaxf((1.f - beta) * h + beta * v, 0.f);
            }
            if (MODE != 0) out_f[(size_t)row * NC + col] = v;
            out_b[(size_t)row * NC + col] = (bf16)v;
        }
    }
}

// sl = h . alp, sr = h . arp  (fp32 — feeds sigma output, keep precise)
__global__ __launch_bounds__(256) void slsr_k(const float* __restrict__ h,
                                              const float* __restrict__ alp,
                                              const float* __restrict__ arp,
                                              float* __restrict__ sl, float* __restrict__ sr,
                                              int n) {
    __shared__ float a[C], b[C];
    if (threadIdx.x < C) { a[threadIdx.x] = alp[threadIdx.x]; b[threadIdx.x] = arp[threadIdx.x]; }
    __syncthreads();
    int i = blockIdx.x * blockDim.x + threadIdx.x;
    if (i >= n) return;
    const float4* hr = (const float4*)(h + (size_t)i * C);
    float s1 = 0.f, s2 = 0.f;
    #pragma unroll 8
    for (int k4 = 0; k4 < C / 4; ++k4) {
        float4 v = hr[k4];
        int k = k4 * 4;
        s1 += v.x * a[k] + v.y * a[k + 1] + v.z * a[k + 2] + v.w * a[k + 3];
        s2 += v.x * b[k] + v.y * b[k + 1] + v.z * b[k + 2] + v.w * b[k + 3];
    }
    sl[i] = s1;
    sr[i] = s2;
}

// per edge: s = sigmoid(leaky_relu(sl[src]+sr[dst])); cpc[csr_pos] = ew*s; cn[dst] += ew*(1-s)
__global__ void edge_k(const int* __restrict__ src, const int* __restrict__ dst,
                       const float* __restrict__ sl, const float* __restrict__ sr,
                       const float* __restrict__ ew, const int* __restrict__ pos_of,
                       float* __restrict__ cpc, float* __restrict__ cn,
                       float* __restrict__ sig_out) {
    int e = blockIdx.x * blockDim.x + threadIdx.x;
    if (e >= EP) return;
    int s, d;
    if (e < NE) { s = src[e]; d = dst[e]; }
    else { s = d = e - NE; }
    float x = sl[s] + sr[d];
    float lr = (x > 0.f) ? x : NEG_SLOPE * x;
    float sg = 1.f / (1.f + expf(-lr));
    sig_out[e] = sg;
    float w = ew[e];
    cpc[pos_of[e]] = w * sg;
    atomicAdd(&cn[d], w * (1.f - sg));
}

// one wave per node, 4 edges in flight (16 lanes per edge, uint4 = 8 bf16 cols per lane)
// agg = sum cpc[j]*xp_b[csr_src[j]] + cn[i]*xn_b[i]; hn = 0.9*agg + 0.1*x0
__global__ __launch_bounds__(256) void agg_k(const int* __restrict__ offs,
                                             const int* __restrict__ csr_src,
                                             const float* __restrict__ cpc,
                                             const float* __restrict__ cn,
                                             const unsigned* __restrict__ xpnb_u,
                                             const float* __restrict__ x0,
                                             float* __restrict__ hn,
                                             unsigned* __restrict__ hnb_u, int n) {
    int wid = (blockIdx.x * blockDim.x + threadIdx.x) >> 6;  // node
    int lane = threadIdx.x & 63;
    if (wid >= n) return;
    int s0 = offs[wid], s1 = offs[wid + 1];
    const int g = lane >> 4;      // edge slot 0..3
    const int cg = lane & 15;     // column group (8 bf16 cols)
    float acc[8];
    #pragma unroll
    for (int i = 0; i < 8; ++i) acc[i] = 0.f;

    for (int j0 = s0; j0 < s1; j0 += 64) {
        int j = j0 + lane;
        int msrc = 0;
        float mcoef = 0.f;
        if (j < s1) { msrc = csr_src[j]; mcoef = cpc[j]; }
        int cnt = min(64, s1 - j0);
        for (int t = 0; t < cnt; t += 4) {
            int idx = t + g;                       // proven <= 63
            float coef = __shfl(mcoef, idx);       // 0 when idx >= cnt
            int srcn = __shfl(msrc, idx);
            uint4 v = *(const uint4*)(xpnb_u + (size_t)srcn * 128 + cg * 4);
            acc[0] += coef * bulo(v.x);
            acc[1] += coef * buhi(v.x);
            acc[2] += coef * bulo(v.y);
            acc[3] += coef * buhi(v.y);
            acc[4] += coef * bulo(v.z);
            acc[5] += coef * buhi(v.z);
            acc[6] += coef * bulo(v.w);
            acc[7] += coef * buhi(v.w);
        }
    }
    // reduce the 4 edge slots
    #pragma unroll
    for (int i = 0; i < 8; ++i) {
        acc[i] += __shfl_xor(acc[i], 16);
        acc[i] += __shfl_xor(acc[i], 32);
    }
    float cni = cn[wid];
    unsigned un = xpnb_u[(size_t)wid * 128 + 64 + cg * 4 + g];   // xn cols cg*8+2g,+1
    float2 v0 = ((const float2*)x0)[(size_t)wid * 64 + cg * 4 + g];
    float ox = (1.f - ALPHA) * (acc[g * 2] + cni * bulo(un)) + ALPHA * v0.x;
    float oy = (1.f - ALPHA) * (acc[g * 2 + 1] + cni * buhi(un)) + ALPHA * v0.y;
    ((float2*)hn)[(size_t)wid * 64 + cg * 4 + g] = make_float2(ox, oy);
    hnb_u[(size_t)wid * 64 + cg * 4 + g] = (unsigned)f2bu(ox) | ((unsigned)f2bu(oy) << 16);
}

// logits + log_softmax (fp32)
__global__ __launch_bounds__(256) void logits_k(const float* __restrict__ h,
                                                const float* __restrict__ w,
                                                const float* __restrict__ b,
                                                float* __restrict__ out, int n) {
    __shared__ float ws[C * NCLS];
    __shared__ float bs[NCLS];
    for (int i = threadIdx.x; i < C * NCLS; i += 256) ws[i] = w[i];
    if (threadIdx.x < NCLS) bs[threadIdx.x] = b[threadIdx.x];
    __syncthreads();
    int i = blockIdx.x * blockDim.x + threadIdx.x;
    if (i >= n) return;
    const float4* hr = (const float4*)(h + (size_t)i * C);
    float acc[NCLS];
    #pragma unroll
    for (int c = 0; c < NCLS; ++c) acc[c] = 0.f;
    for (int k4 = 0; k4 < C / 4; ++k4) {
        float4 v = hr[k4];
        int k = k4 * 4;
        #pragma unroll
        for (int c = 0; c < NCLS; ++c) {
            acc[c] += v.x * ws[k * NCLS + c] + v.y * ws[(k + 1) * NCLS + c] +
                      v.z * ws[(k + 2) * NCLS + c] + v.w * ws[(k + 3) * NCLS + c];
        }
    }
    float lg[NCLS], m = -1e30f;
    #pragma unroll
    for (int c = 0; c < NCLS; ++c) { lg[c] = acc[c] + bs[c]; m = fmaxf(m, lg[c]); }
    float sum = 0.f;
    #pragma unroll
    for (int c = 0; c < NCLS; ++c) sum += expf(lg[c] - m);
    float lse = m + logf(sum);
    #pragma unroll
    for (int c = 0; c < NCLS; ++c) out[(size_t)i * NCLS + c] = lg[c] - lse;
}

extern "C" void kernel_launch(void* const* d_in, const int* in_sizes, int n_in,
                              void* d_out, int out_size, void* d_ws, size_t ws_size,
                              hipStream_t stream) {
    (void)in_sizes; (void)n_in; (void)out_size; (void)ws_size;
    const float* x      = (const float*)d_in[0];
    const int*   eidx   = (const int*)d_in[1];
    const float* lin0_w = (const float*)d_in[2];
    const float* lin0_b = (const float*)d_in[3];
    const float* lin1_w = (const float*)d_in[4];
    const float* lin1_b = (const float*)d_in[5];
    const float* lin_w  = (const float*)d_in[6];
    const float* att_l  = (const float*)d_in[7];
    const float* att_r  = (const float*)d_in[8];
    const float* w_p    = (const float*)d_in[9];
    const float* w_n    = (const float*)d_in[10];
    const float* w1     = (const float*)d_in[11];
    float* outp = (float*)d_out;
    float* sig_base = outp + (size_t)NN * NCLS;   // sigmas [L, EP]

    const int* srcA = eidx;
    const int* dstA = eidx + NE;

    // ---------------- workspace carve-up ----------------
    float* f = (float*)d_ws;
    float* x0   = f; f += (size_t)NN * C;
    float* hF   = f; f += (size_t)NN * C;
    float* hn   = f; f += (size_t)NN * C;
    float* sl   = f; f += NN;
    float* sr   = f; f += NN;
    float* cpc  = f; f += EP;
    float* ew   = f; f += EP;
    float* cn   = f; f += NN;
    float* dinv = f; f += NN;
    float* alp  = f; f += NL * C;
    float* arp  = f; f += NL * C;
    // bf16 region (16B aligned: preceding float counts are multiples of 4)
    bf16* bp = (bf16*)f;
    bf16* xb    = bp;                               // overlays xpnb..hb (dead after lin0)
    bf16* xpnb  = bp;  bp += (size_t)NN * 2 * C;
    bf16* hnb   = bp;  bp += (size_t)NN * C;
    bf16* hb    = bp;  bp += (size_t)NN * C;
    bf16* x0b   = bp;  bp += (size_t)NN * C;
    bf16* wpnt  = bp;  bp += (size_t)NL * 16 * 4 * 64 * 8;
    bf16* w1t   = bp;  bp += (size_t)NL * 8 * 4 * 64 * 8;
    bf16* lin0t = bp;  bp += (size_t)8 * 16 * 64 * 8;
    int* ip = (int*)bp;
    int* deg     = ip; ip += NN;
    int* offs    = ip; ip += NN + 4;
    int* cursor  = ip; ip += NN;
    int* csr_src = ip; ip += EP;
    int* pos_of  = ip; ip += EP;
    int* exoff   = ip; ip += NN;
    int* bsum    = ip; ip += SCB;
    int* boff    = ip; ip += SCB;

    dim3 B(256);
    int gN   = (NN + 255) / 256;
    int gE   = (NE + 255) / 256;
    int gEP  = (EP + 255) / 256;
    int gM64 = (NN + 63) / 64;       // 782 blocks for MFMA GEMMs
    int gAgg = NN / 4;               // one wave per node

    // ---- graph prep ----
    fill_i32_k<<<gN, B, 0, stream>>>(deg, 1, NN);
    count_deg_k<<<gE, B, 0, stream>>>(dstA, deg, NE);
    dinv_k<<<gN, B, 0, stream>>>(deg, dinv, NN);
    scan1_k<<<NSB, SCB, 0, stream>>>(deg, exoff, bsum, NN);
    scan2_k<<<1, SCB, 0, stream>>>(bsum, boff, NSB);
    scan3_k<<<NSB, SCB, 0, stream>>>(exoff, boff, offs, cursor, NN);
    ew_k<<<gEP, B, 0, stream>>>(srcA, dstA, dinv, ew);
    csr_fill_k<<<gEP, B, 0, stream>>>(srcA, dstA, cursor, csr_src, pos_of);
    attproj_k<<<NL, C, 0, stream>>>(lin_w, att_l, att_r, alp, arp);

    // ---- weight packs + input conversion ----
    wpn_trans_k<<<dim3(64, NL), 64, 0, stream>>>(w_p, w_n, wpnt);
    w1_trans_k<<<dim3(32, NL), 64, 0, stream>>>(w1, w1t);
    lin0_trans_k<<<128, 64, 0, stream>>>(lin0_w, lin0t);
    conv_x_k<<<(NN * KPAD + 255) / 256, B, 0, stream>>>(x, xb);

    // ---- x0 = relu(x @ lin0_w + b) ----
    mgemm_k<8, 16, 1><<<gM64, B, 0, stream>>>(xb, lin0t, NN, lin0_b, nullptr, 0.f, x0, x0b);

    // ---- layers ----
    const float* cur = x0;
    const bf16* curb = x0b;
    for (int l = 0; l < NL; ++l) {
        float beta = (float)log(0.5 / (double)(l + 1) + 1.0);
        mgemm_k<16, 4, 0><<<gM64, B, 0, stream>>>(curb, wpnt + (size_t)l * 16 * 4 * 64 * 8,
                                                  NN, nullptr, nullptr, 0.f, nullptr, xpnb);
        slsr_k<<<gN, B, 0, stream>>>(cur, alp + l * C, arp + l * C, sl, sr, NN);
        fill_f32_k<<<gN, B, 0, stream>>>(cn, 0.f, NN);
        edge_k<<<gEP, B, 0, stream>>>(srcA, dstA, sl, sr, ew, pos_of, cpc, cn,
                                      sig_base + (size_t)l * EP);
        agg_k<<<gAgg, B, 0, stream>>>(offs, csr_src, cpc, cn, (const unsigned*)xpnb,
                                      x0, hn, (unsigned*)hnb, NN);
        mgemm_k<8, 4, 2><<<gM64, B, 0, stream>>>(hnb, w1t + (size_t)l * 8 * 4 * 64 * 8,
                                                 NN, nullptr, hn, beta, hF, hb);
        cur = hF;
        curb = hb;
    }

    // ---- logits + log_softmax ----
    logits_k<<<gN, B, 0, stream>>>(cur, lin1_w, lin1_b, outp, NN);
}